// Round 22
// baseline (85.777 us; speedup 1.0000x reference)
//
#include <hip/hip_runtime.h>

#define NB 2
#define SQL 256
#define NH 16
#define HD 64
#define EMB 1024

typedef unsigned short ushortT;
typedef unsigned int uintT;
typedef __attribute__((ext_vector_type(8))) short bf16x8;
typedef __attribute__((ext_vector_type(4))) float f32x4;
typedef __attribute__((ext_vector_type(2))) float f32x2;

// log2(e) / sqrt(EMBED): folded into Wq so softmax = 2^(q*k)
__device__ __constant__ float kQSCALE = 1.4426950408889634f / 32.0f;

__device__ __forceinline__ float fexp2(float x) { return __builtin_amdgcn_exp2f(x); }
__device__ __forceinline__ float frcp(float x)  { return __builtin_amdgcn_rcpf(x); }

__device__ __forceinline__ ushortT f2bf(float x) {
    uintT u = __float_as_uint(x);
    u += 0x7fffu + ((u >> 16) & 1u);        // RNE
    return (ushortT)(u >> 16);
}
__device__ __forceinline__ ushort4 f2bf4(float4 a) {
    return make_ushort4(f2bf(a.x), f2bf(a.y), f2bf(a.z), f2bf(a.w));
}
// unpack one uint32 = 2 bf16 (lo = even channel, hi = odd channel) -> f32x2
__device__ __forceinline__ f32x2 unpk2(uintT u) {
    f32x2 r;
    r.x = __uint_as_float(u << 16);
    r.y = __uint_as_float(u & 0xffff0000u);
    return r;
}
// pair-sum via DPP quad_perm [1,0,3,2]: lane(2i) <-> lane(2i+1). VALU pipe.
__device__ __forceinline__ float pairsum_dpp(float u) {
    const int j = __builtin_amdgcn_mov_dpp(__float_as_int(u), 0xB1, 0xF, 0xF, true);
    return u + __int_as_float(j);
}

// ---------------------------------------------------------------------------
// Kernel 1: q/k/v projections via bf16 MFMA (16x16x32). Block = 2 (n,s) rows.
// Folds: AO = 0 (attn atomic target), Wo -> bf16 (Wob). Grid 256 x 256.
// ---------------------------------------------------------------------------
__global__ __launch_bounds__(256) void qkv_kernel(
    const float* __restrict__ x,
    const float* __restrict__ Wq,
    const float* __restrict__ Wk,
    const float* __restrict__ Wv,
    const float* __restrict__ Wo,
    ushortT* __restrict__ Q,
    ushortT* __restrict__ K,
    ushortT* __restrict__ V,
    float* __restrict__ AO,
    ushortT* __restrict__ Wob)
{
    __shared__ ushortT wls[3][64 * 72];
    __shared__ ushortT xs[2][16 * 72];

    const int tid = threadIdx.x;
    const int ns0 = blockIdx.x * 2;
    const int g   = blockIdx.x * 256 + tid;   // 65536 threads total

    // fold: AO = 0 (2 float4/thread)
    {
        const float4 z = make_float4(0.f, 0.f, 0.f, 0.f);
        ((float4*)AO)[g] = z;
        ((float4*)AO)[g + 65536] = z;
    }
    // fold: Wo -> bf16 (1M floats, 4 float4/thread)
#pragma unroll
    for (int j = 0; j < 4; ++j) {
        const int f4 = j * 65536 + g;
        ((ushort4*)Wob)[f4] = f2bf4(((const float4*)Wo)[f4]);
    }

#pragma unroll
    for (int m = 0; m < 3; ++m) {
        const float4* src = (m == 0) ? (const float4*)Wq
                          : (m == 1) ? (const float4*)Wk : (const float4*)Wv;
#pragma unroll
        for (int j = 0; j < 4; ++j) {
            const int idx = j * 256 + tid;
            const int e   = idx >> 4;
            const int d4  = idx & 15;
            float4 a = src[idx];
            if (m == 0) { a.x *= kQSCALE; a.y *= kQSCALE; a.z *= kQSCALE; a.w *= kQSCALE; }
            *(ushort4*)&wls[m][e * 72 + d4 * 4] = f2bf4(a);
        }
    }
#pragma unroll
    for (int j = 0; j < 2; ++j) {
        const int idx = j * 256 + tid;
        const int r   = idx >> 8;
        const int h   = (idx >> 4) & 15;
        const int d4  = idx & 15;
        const float4 a = ((const float4*)(x + (size_t)(ns0 + r) * EMB))[idx & 255];
        *(ushort4*)&xs[r][h * 72 + d4 * 4] = f2bf4(a);
    }
    __syncthreads();

    const int w   = tid >> 6;
    const int nsr = w >> 1;
    const int eb0 = (w & 1) * 32;
    const int l   = tid & 63;
    const int lr  = l & 15;
    const int lk  = l >> 4;

    const bf16x8 a0 = *(const bf16x8*)&xs[nsr][lr * 72 + lk * 8];
    const bf16x8 a1 = *(const bf16x8*)&xs[nsr][lr * 72 + 32 + lk * 8];

#pragma unroll
    for (int m = 0; m < 3; ++m) {
        ushortT* outp = (m == 0) ? Q : (m == 1) ? K : V;
#pragma unroll
        for (int ef = 0; ef < 2; ++ef) {
            const int eb = eb0 + ef * 16;
            const bf16x8 b0 = *(const bf16x8*)&wls[m][(eb + lr) * 72 + lk * 8];
            const bf16x8 b1 = *(const bf16x8*)&wls[m][(eb + lr) * 72 + 32 + lk * 8];
            f32x4 c = {0.f, 0.f, 0.f, 0.f};
            c = __builtin_amdgcn_mfma_f32_16x16x32_bf16(a0, b0, c, 0, 0, 0);
            c = __builtin_amdgcn_mfma_f32_16x16x32_bf16(a1, b1, c, 0, 0, 0);
            ushortT* dst = outp + (size_t)(ns0 + nsr) * EMB + (eb + lr) * 16 + lk * 4;
            *(ushort4*)dst = make_ushort4(f2bf(c[0]), f2bf(c[1]), f2bf(c[2]), f2bf(c[3]));
        }
    }
}

// ---------------------------------------------------------------------------
// Kernel 2: fused energy -> softmax(h) -> sum(t). ROUND-22 RESTRUCTURE:
// the 4 waves of a block own DIFFERENT s-rows (2 each, 8/block) and SHARE
// the K/V t-tiles through double-buffered LDS (8 t x 1KB x {K,V} x 2buf =
// 32KB): global K/V traffic drops 4x (262 -> 64 MB; L1 delivery was ~7us
// of attn's ~25). Single barrier per tile (write buf -> barrier -> compute
// buf; alternating buffers make it race-free). Each wave stages 4 rows/tile
// (reg -> ds_write_b128), prefetching tile i+1 before computing tile i.
// Inner ATTN_STEP identical to round-21, fed by ds_read_b128.
// Waves own disjoint s -> no cross-wave reduce; 16 atomicAdd/thread.
// Grid = 2n * 32sg(8s) * 2eh * 8tw(32 t-steps) = 1024 blocks x 256 thr
// (4 blocks/CU by LDS, 16 waves/CU).
// ---------------------------------------------------------------------------
#define ATTN_STEP(KU4, VU4)                                                    \
    {                                                                          \
        f32x2 k2[4], v2[4], p0[4], p1[4];                                      \
        k2[0] = unpk2(KU4.x); k2[1] = unpk2(KU4.y);                            \
        k2[2] = unpk2(KU4.z); k2[3] = unpk2(KU4.w);                            \
        _Pragma("unroll")                                                      \
        for (int j = 0; j < 4; ++j) {                                          \
            const f32x2 x0 = q0_2[j] * k2[j];                                  \
            const f32x2 x1 = q1_2[j] * k2[j];                                  \
            p0[j].x = fexp2(x0.x); p0[j].y = fexp2(x0.y);                      \
            p1[j].x = fexp2(x1.x); p1[j].y = fexp2(x1.y);                      \
        }                                                                      \
        const f32x2 s0v = (p0[0] + p0[1]) + (p0[2] + p0[3]);                   \
        const f32x2 s1v = (p1[0] + p1[1]) + (p1[2] + p1[3]);                   \
        const float rs0 = frcp(pairsum_dpp(s0v.x + s0v.y));                    \
        const float rs1 = frcp(pairsum_dpp(s1v.x + s1v.y));                    \
        const f32x2 rb0 = {rs0, rs0};                                          \
        const f32x2 rb1 = {rs1, rs1};                                          \
        v2[0] = unpk2(VU4.x); v2[1] = unpk2(VU4.y);                            \
        v2[2] = unpk2(VU4.z); v2[3] = unpk2(VU4.w);                            \
        _Pragma("unroll")                                                      \
        for (int j = 0; j < 4; ++j) {                                          \
            acc0[j] = __builtin_elementwise_fma(v2[j] * rb0, p0[j], acc0[j]);  \
            acc1[j] = __builtin_elementwise_fma(v2[j] * rb1, p1[j], acc1[j]);  \
        }                                                                      \
    }

__global__ __launch_bounds__(256) void attn_kernel(
    const ushortT* __restrict__ Q,
    const ushortT* __restrict__ K,
    const ushortT* __restrict__ V,
    float* __restrict__ AO)
{
    // [buf][m][t][ch]: ((buf*2+m)*8+t)*512 + ch   -> 32 KB
    __shared__ ushortT kv[2 * 2 * 8 * 512];

    const int b    = blockIdx.x;
    const int tw   = b & 7;
    const int eh   = (b >> 3) & 1;
    const int sg   = (b >> 4) & 31;
    const int n    = b >> 9;
    const int tid  = threadIdx.x;
    const int wave = tid >> 6;
    const int l    = tid & 63;
    const int s0   = sg * 8 + wave * 2;   // wave-private 2 s-rows
    const int tB   = tw * 32;             // block t-window: 32 steps, 4 tiles

    f32x2 q0_2[4], q1_2[4];
    {
        const uint4* qp = (const uint4*)(Q + (size_t)(n * SQL + s0) * EMB + 512 * eh) + l;
        const uint4 qa = qp[0];
        const uint4 qb = qp[128];   // next s row
        q0_2[0] = unpk2(qa.x); q0_2[1] = unpk2(qa.y);
        q0_2[2] = unpk2(qa.z); q0_2[3] = unpk2(qa.w);
        q1_2[0] = unpk2(qb.x); q1_2[1] = unpk2(qb.y);
        q1_2[2] = unpk2(qb.z); q1_2[3] = unpk2(qb.w);
    }

    f32x2 acc0[4], acc1[4];
#pragma unroll
    for (int j = 0; j < 4; ++j) {
        acc0[j] = (f32x2){0.f, 0.f};
        acc1[j] = (f32x2){0.f, 0.f};
    }

    // staging: wave stages K rows {wave, 4+wave} and V rows {wave, 4+wave}
    const ushortT* Kb = K + (size_t)(n * SQL + tB) * EMB + 512 * eh + l * 8;
    const ushortT* Vb = V + (size_t)(n * SQL + tB) * EMB + 512 * eh + l * 8;
    const int rA = wave, rB = 4 + wave;

    uint4 sk0 = *(const uint4*)&Kb[(size_t)rA * EMB];
    uint4 sk1 = *(const uint4*)&Kb[(size_t)rB * EMB];
    uint4 sv0 = *(const uint4*)&Vb[(size_t)rA * EMB];
    uint4 sv1 = *(const uint4*)&Vb[(size_t)rB * EMB];

#pragma unroll
    for (int tile = 0; tile < 4; ++tile) {
        const int buf = tile & 1;
        ushortT* kbuf = &kv[(buf * 2 + 0) * 8 * 512];
        ushortT* vbuf = &kv[(buf * 2 + 1) * 8 * 512];
        *(uint4*)&kbuf[rA * 512 + l * 8] = sk0;
        *(uint4*)&kbuf[rB * 512 + l * 8] = sk1;
        *(uint4*)&vbuf[rA * 512 + l * 8] = sv0;
        *(uint4*)&vbuf[rB * 512 + l * 8] = sv1;
        __syncthreads();
        if (tile < 3) {   // prefetch next tile's rows (hidden under compute)
            const size_t off = (size_t)(tile + 1) * 8 * EMB;
            sk0 = *(const uint4*)&Kb[off + (size_t)rA * EMB];
            sk1 = *(const uint4*)&Kb[off + (size_t)rB * EMB];
            sv0 = *(const uint4*)&Vb[off + (size_t)rA * EMB];
            sv1 = *(const uint4*)&Vb[off + (size_t)rB * EMB];
        }
#pragma unroll
        for (int t = 0; t < 8; ++t) {
            const uint4 ku = *(const uint4*)&kbuf[t * 512 + l * 8];
            const uint4 vu = *(const uint4*)&vbuf[t * 512 + l * 8];
            ATTN_STEP(ku, vu);
        }
        // no trailing barrier: next iteration writes the OTHER buffer, and
        // its barrier orders those writes against all waves' reads.
    }

    // element = 512eh + 8l + c -> AO channel = 512(l&1) + 64c + 32eh + (l>>1)
    float* aob = AO + (size_t)(n * SQL + s0) * EMB + 512 * (l & 1) + 32 * eh + (l >> 1);
#pragma unroll
    for (int j = 0; j < 4; ++j) {
        atomicAdd(aob + 64 * (2 * j),           acc0[j].x);
        atomicAdd(aob + 64 * (2 * j + 1),       acc0[j].y);
        atomicAdd(aob + EMB + 64 * (2 * j),     acc1[j].x);
        atomicAdd(aob + EMB + 64 * (2 * j + 1), acc1[j].y);
    }
}

// ---------------------------------------------------------------------------
// Kernel 3: out = AO @ Wob^T + bias via bf16 MFMA. 32r x 64j tile, FULL K
// (32 k-steps) with register prefetch of next k-step's A/B. Plain stores +
// fused bias -> zero atomics. Grid = 16rt * 16jt = 256 blocks x 256 threads.
// ---------------------------------------------------------------------------
__global__ __launch_bounds__(256) void proj_kernel(
    const float* __restrict__ AO,
    const ushortT* __restrict__ Wob,
    const float* __restrict__ bo,
    float* __restrict__ out)
{
    __shared__ ushortT As[32 * 40];
    __shared__ ushortT Bs[64 * 40];

    const int b  = blockIdx.x;     // 0..255
    const int jt = b & 15;         // cols
    const int rt = b >> 4;         // 0..15 -> 512 rows
    const int tid = threadIdx.x;
    const int r0 = rt * 32, j0 = jt * 64;

    const int w  = tid >> 6;
    const int wr = w >> 1;         // 16-row half
    const int wc = w & 1;          // 32-col half
    const int l  = tid & 63;
    const int lr = l & 15;
    const int lk = l >> 4;

    const int arow = tid >> 3, akq = tid & 7;   // A: 32r x 32k = 256 float4
    const int brow = tid >> 2, bko = tid & 3;   // B: 64r x 32k = 256 uint4

    f32x4 c0 = {0.f, 0.f, 0.f, 0.f};
    f32x4 c1 = {0.f, 0.f, 0.f, 0.f};

    float4 aN = *(const float4*)&AO[(size_t)(r0 + arow) * EMB + akq * 4];
    uint4  bN = *(const uint4*)&Wob[(size_t)(j0 + brow) * EMB + bko * 8];

    for (int kt = 0; kt < 32; ++kt) {
        __syncthreads();
        *(ushort4*)&As[arow * 40 + akq * 4] = f2bf4(aN);
        *(uint4*)&Bs[brow * 40 + bko * 8] = bN;
        if (kt < 31) {                       // prefetch k-step kt+1
            const int kb = (kt + 1) * 32;
            aN = *(const float4*)&AO[(size_t)(r0 + arow) * EMB + kb + akq * 4];
            bN = *(const uint4*)&Wob[(size_t)(j0 + brow) * EMB + kb + bko * 8];
        }
        __syncthreads();

        const bf16x8 a  = *(const bf16x8*)&As[(wr * 16 + lr) * 40 + lk * 8];
        const bf16x8 b0 = *(const bf16x8*)&Bs[(wc * 32 + lr) * 40 + lk * 8];
        const bf16x8 b1 = *(const bf16x8*)&Bs[(wc * 32 + 16 + lr) * 40 + lk * 8];
        c0 = __builtin_amdgcn_mfma_f32_16x16x32_bf16(a, b0, c0, 0, 0, 0);
        c1 = __builtin_amdgcn_mfma_f32_16x16x32_bf16(a, b1, c1, 0, 0, 0);
    }

    const int rbase = r0 + wr * 16 + lk * 4;
    const int jbase = j0 + wc * 32 + lr;
    const float bb0 = bo[jbase];
    const float bb1 = bo[jbase + 16];
#pragma unroll
    for (int e = 0; e < 4; ++e) {
        out[(size_t)(rbase + e) * EMB + jbase]      = c0[e] + bb0;
        out[(size_t)(rbase + e) * EMB + jbase + 16] = c1[e] + bb1;
    }
}

extern "C" void kernel_launch(void* const* d_in, const int* in_sizes, int n_in,
                              void* d_out, int out_size, void* d_ws, size_t ws_size,
                              hipStream_t stream)
{
    const float* x  = (const float*)d_in[0];
    const float* Wq = (const float*)d_in[1];
    const float* Wk = (const float*)d_in[2];
    const float* Wv = (const float*)d_in[3];
    const float* Wo = (const float*)d_in[4];
    const float* bo = (const float*)d_in[5];

    float* ws = (float*)d_ws;
    ushortT* Q   = (ushortT*)ws;              // 524288 bf16 = 1 MB
    ushortT* K   = (ushortT*)(ws + 262144);   // 1 MB
    ushortT* V   = (ushortT*)(ws + 524288);   // 1 MB
    float*   AO  = ws + 786432;               // 524288 f32 = 2 MB
    ushortT* Wob = (ushortT*)(ws + 1310720);  // 1048576 bf16 = 2 MB

    qkv_kernel<<<256, 256, 0, stream>>>(x, Wq, Wk, Wv, Wo, Q, K, V, AO, Wob);
    attn_kernel<<<1024, 256, 0, stream>>>(Q, K, V, AO);
    proj_kernel<<<256, 256, 0, stream>>>(AO, Wob, bo, (float*)d_out);
}

// Round 23
// 50.197 us; speedup vs baseline: 1.7088x; 1.7088x over previous
//
#include <hip/hip_runtime.h>

#define NB 2
#define SQL 256
#define NH 16
#define HD 64
#define EMB 1024

typedef unsigned short ushortT;
typedef unsigned int uintT;
typedef __attribute__((ext_vector_type(8))) short bf16x8;
typedef __attribute__((ext_vector_type(4))) float f32x4;
typedef __attribute__((ext_vector_type(2))) float f32x2;

// log2(e) / sqrt(EMBED): folded into Wq so softmax = 2^(q*k)
__device__ __constant__ float kQSCALE = 1.4426950408889634f / 32.0f;

__device__ __forceinline__ float fexp2(float x) { return __builtin_amdgcn_exp2f(x); }
__device__ __forceinline__ float frcp(float x)  { return __builtin_amdgcn_rcpf(x); }

__device__ __forceinline__ ushortT f2bf(float x) {
    uintT u = __float_as_uint(x);
    u += 0x7fffu + ((u >> 16) & 1u);        // RNE
    return (ushortT)(u >> 16);
}
__device__ __forceinline__ ushort4 f2bf4(float4 a) {
    return make_ushort4(f2bf(a.x), f2bf(a.y), f2bf(a.z), f2bf(a.w));
}
// unpack one uint32 = 2 bf16 (lo = even channel, hi = odd channel) -> f32x2
__device__ __forceinline__ f32x2 unpk2(uintT u) {
    f32x2 r;
    r.x = __uint_as_float(u << 16);
    r.y = __uint_as_float(u & 0xffff0000u);
    return r;
}
// pair-sum via DPP quad_perm [1,0,3,2]: lane(2i) <-> lane(2i+1). VALU pipe.
__device__ __forceinline__ float pairsum_dpp(float u) {
    const int j = __builtin_amdgcn_mov_dpp(__float_as_int(u), 0xB1, 0xF, 0xF, true);
    return u + __int_as_float(j);
}

// ---------------------------------------------------------------------------
// Kernel 1: q/k/v projections via bf16 MFMA (16x16x32). Block = 2 (n,s) rows.
// Folds: AO = 0 (attn atomic target), Wo -> bf16 (Wob). Grid 256 x 256.
// (Round-21 version verbatim.)
// ---------------------------------------------------------------------------
__global__ __launch_bounds__(256) void qkv_kernel(
    const float* __restrict__ x,
    const float* __restrict__ Wq,
    const float* __restrict__ Wk,
    const float* __restrict__ Wv,
    const float* __restrict__ Wo,
    ushortT* __restrict__ Q,
    ushortT* __restrict__ K,
    ushortT* __restrict__ V,
    float* __restrict__ AO,
    ushortT* __restrict__ Wob)
{
    __shared__ ushortT wls[3][64 * 72];
    __shared__ ushortT xs[2][16 * 72];

    const int tid = threadIdx.x;
    const int ns0 = blockIdx.x * 2;
    const int g   = blockIdx.x * 256 + tid;   // 65536 threads total

    // fold: AO = 0 (2 float4/thread)
    {
        const float4 z = make_float4(0.f, 0.f, 0.f, 0.f);
        ((float4*)AO)[g] = z;
        ((float4*)AO)[g + 65536] = z;
    }
    // fold: Wo -> bf16 (1M floats, 4 float4/thread)
#pragma unroll
    for (int j = 0; j < 4; ++j) {
        const int f4 = j * 65536 + g;
        ((ushort4*)Wob)[f4] = f2bf4(((const float4*)Wo)[f4]);
    }

#pragma unroll
    for (int m = 0; m < 3; ++m) {
        const float4* src = (m == 0) ? (const float4*)Wq
                          : (m == 1) ? (const float4*)Wk : (const float4*)Wv;
#pragma unroll
        for (int j = 0; j < 4; ++j) {
            const int idx = j * 256 + tid;
            const int e   = idx >> 4;
            const int d4  = idx & 15;
            float4 a = src[idx];
            if (m == 0) { a.x *= kQSCALE; a.y *= kQSCALE; a.z *= kQSCALE; a.w *= kQSCALE; }
            *(ushort4*)&wls[m][e * 72 + d4 * 4] = f2bf4(a);
        }
    }
#pragma unroll
    for (int j = 0; j < 2; ++j) {
        const int idx = j * 256 + tid;
        const int r   = idx >> 8;
        const int h   = (idx >> 4) & 15;
        const int d4  = idx & 15;
        const float4 a = ((const float4*)(x + (size_t)(ns0 + r) * EMB))[idx & 255];
        *(ushort4*)&xs[r][h * 72 + d4 * 4] = f2bf4(a);
    }
    __syncthreads();

    const int w   = tid >> 6;
    const int nsr = w >> 1;
    const int eb0 = (w & 1) * 32;
    const int l   = tid & 63;
    const int lr  = l & 15;
    const int lk  = l >> 4;

    const bf16x8 a0 = *(const bf16x8*)&xs[nsr][lr * 72 + lk * 8];
    const bf16x8 a1 = *(const bf16x8*)&xs[nsr][lr * 72 + 32 + lk * 8];

#pragma unroll
    for (int m = 0; m < 3; ++m) {
        ushortT* outp = (m == 0) ? Q : (m == 1) ? K : V;
#pragma unroll
        for (int ef = 0; ef < 2; ++ef) {
            const int eb = eb0 + ef * 16;
            const bf16x8 b0 = *(const bf16x8*)&wls[m][(eb + lr) * 72 + lk * 8];
            const bf16x8 b1 = *(const bf16x8*)&wls[m][(eb + lr) * 72 + 32 + lk * 8];
            f32x4 c = {0.f, 0.f, 0.f, 0.f};
            c = __builtin_amdgcn_mfma_f32_16x16x32_bf16(a0, b0, c, 0, 0, 0);
            c = __builtin_amdgcn_mfma_f32_16x16x32_bf16(a1, b1, c, 0, 0, 0);
            ushortT* dst = outp + (size_t)(ns0 + nsr) * EMB + (eb + lr) * 16 + lk * 4;
            *(ushort4*)dst = make_ushort4(f2bf(c[0]), f2bf(c[1]), f2bf(c[2]), f2bf(c[3]));
        }
    }
}

// ---------------------------------------------------------------------------
// Kernel 2: fused energy -> softmax(h) -> sum(t). ROUND-21 VERSION VERBATIM
// (measured best: total 48.1us). Wave = 2 s-streams x 8ch packed f32x2, DPP
// pair-sum, ping-pong reg prefetch; 4 waves split a 64-wide t-window; LDS
// tree-reduce; 4 atomicAdd/thread (2M total).
// Grid = 2n * 128sg * 2eh * 4tw = 2048 blocks x 256 threads (8 waves/SIMD).
// ---------------------------------------------------------------------------
#define ATTN_STEP(KU4, VU4)                                                    \
    {                                                                          \
        f32x2 k2[4], v2[4], p0[4], p1[4];                                      \
        k2[0] = unpk2(KU4.x); k2[1] = unpk2(KU4.y);                            \
        k2[2] = unpk2(KU4.z); k2[3] = unpk2(KU4.w);                            \
        _Pragma("unroll")                                                      \
        for (int j = 0; j < 4; ++j) {                                          \
            const f32x2 x0 = q0_2[j] * k2[j];                                  \
            const f32x2 x1 = q1_2[j] * k2[j];                                  \
            p0[j].x = fexp2(x0.x); p0[j].y = fexp2(x0.y);                      \
            p1[j].x = fexp2(x1.x); p1[j].y = fexp2(x1.y);                      \
        }                                                                      \
        const f32x2 s0v = (p0[0] + p0[1]) + (p0[2] + p0[3]);                   \
        const f32x2 s1v = (p1[0] + p1[1]) + (p1[2] + p1[3]);                   \
        const float rs0 = frcp(pairsum_dpp(s0v.x + s0v.y));                    \
        const float rs1 = frcp(pairsum_dpp(s1v.x + s1v.y));                    \
        const f32x2 rb0 = {rs0, rs0};                                          \
        const f32x2 rb1 = {rs1, rs1};                                          \
        v2[0] = unpk2(VU4.x); v2[1] = unpk2(VU4.y);                            \
        v2[2] = unpk2(VU4.z); v2[3] = unpk2(VU4.w);                            \
        _Pragma("unroll")                                                      \
        for (int j = 0; j < 4; ++j) {                                          \
            acc0[j] = __builtin_elementwise_fma(v2[j] * rb0, p0[j], acc0[j]);  \
            acc1[j] = __builtin_elementwise_fma(v2[j] * rb1, p1[j], acc1[j]);  \
        }                                                                      \
    }

__global__ __launch_bounds__(256) void attn_kernel(
    const ushortT* __restrict__ Q,
    const ushortT* __restrict__ K,
    const ushortT* __restrict__ V,
    float* __restrict__ AO)
{
    __shared__ float red[16][256];   // 16 KB, bank-conflict-free

    const int b    = blockIdx.x;
    const int tw   = b & 3;
    const int eh   = (b >> 2) & 1;
    const int sg   = (b >> 3) & 127;
    const int n    = b >> 10;
    const int wave = threadIdx.x >> 6;
    const int l    = threadIdx.x & 63;
    const int s0   = sg * 2;
    const int t0   = tw * 64 + wave * 16;   // each wave: 16 t-steps

    f32x2 q0_2[4], q1_2[4];
    {
        const uint4* qp = (const uint4*)(Q + (size_t)(n * SQL + s0) * EMB + 512 * eh) + l;
        const uint4 qa = qp[0];
        const uint4 qb = qp[128];   // next s row
        q0_2[0] = unpk2(qa.x); q0_2[1] = unpk2(qa.y);
        q0_2[2] = unpk2(qa.z); q0_2[3] = unpk2(qa.w);
        q1_2[0] = unpk2(qb.x); q1_2[1] = unpk2(qb.y);
        q1_2[2] = unpk2(qb.z); q1_2[3] = unpk2(qb.w);
    }

    f32x2 acc0[4], acc1[4];
#pragma unroll
    for (int j = 0; j < 4; ++j) {
        acc0[j] = (f32x2){0.f, 0.f};
        acc1[j] = (f32x2){0.f, 0.f};
    }

    const uint4* kp = (const uint4*)(K + (size_t)(n * SQL + t0) * EMB + 512 * eh) + l;
    const uint4* vp = (const uint4*)(V + (size_t)(n * SQL + t0) * EMB + 512 * eh) + l;

    uint4 ka = kp[0];      // k(t)
    uint4 kb = kp[128];    // k(t+1)
    uint4 va = vp[0];      // v(t)

#pragma unroll
    for (int tt = 0; tt < 14; tt += 2) {
        const uint4 kn2 = kp[256];   // k(t+2)
        const uint4 vb  = vp[128];   // v(t+1)
        ATTN_STEP(ka, va);           // consume t
        const uint4 kn3 = kp[384];   // k(t+3)
        va = vp[256];                // v(t+2)
        kp += 256; vp += 256;
        ATTN_STEP(kb, vb);           // consume t+1
        ka = kn2; kb = kn3;
    }
    {   // peeled final pair: no prefetch -> zero over-reads
        const uint4 vb = vp[128];
        ATTN_STEP(ka, va);
        ATTN_STEP(kb, vb);
    }

    // ---- cross-wave LDS reduction: value i = s*8 + c (s in {0,1}, c in 0..7)
#pragma unroll
    for (int j = 0; j < 4; ++j) {
        red[2 * j        ][wave * 64 + l] = acc0[j].x;
        red[2 * j + 1    ][wave * 64 + l] = acc0[j].y;
        red[8 + 2 * j    ][wave * 64 + l] = acc1[j].x;
        red[8 + 2 * j + 1][wave * 64 + l] = acc1[j].y;
    }
    __syncthreads();

    // element = 512eh + 8l + c -> AO channel = 512(l&1) + 64c + 32eh + (l>>1)
    float* aob = AO + (size_t)(n * SQL + s0) * EMB + 512 * (l & 1) + 32 * eh + (l >> 1);
#pragma unroll
    for (int di = 0; di < 4; ++di) {
        const int i = wave * 4 + di;
        const float sum = (red[i][l] + red[i][64 + l]) + (red[i][128 + l] + red[i][192 + l]);
        const int s = i >> 3;
        const int c = i & 7;
        atomicAdd(aob + (size_t)s * EMB + 64 * c, sum);
    }
}

// ---------------------------------------------------------------------------
// Kernel 3: out = AO @ Wob^T + bias via bf16 MFMA. ROUND-23 CHANGE: tile
// 32r x 32j (was 32x64) -> grid 512 = 2 blocks/CU = 8 waves/CU, doubling
// TLP on the latency-exposed k-loop. Each wave owns one 16x16 quadrant;
// B staged by waves 0-1 only (wave-uniform branch). Register prefetch of
// next k-step kept. Plain stores + fused bias, zero atomics.
// Grid = 16rt * 32jt = 512 blocks x 256 threads.
// ---------------------------------------------------------------------------
__global__ __launch_bounds__(256) void proj_kernel(
    const float* __restrict__ AO,
    const ushortT* __restrict__ Wob,
    const float* __restrict__ bo,
    float* __restrict__ out)
{
    __shared__ ushortT As[32 * 40];
    __shared__ ushortT Bs[32 * 40];

    const int b  = blockIdx.x;     // 0..511
    const int jt = b & 31;         // 0..31 -> 1024 cols
    const int rt = b >> 5;         // 0..15 -> 512 rows
    const int tid = threadIdx.x;
    const int r0 = rt * 32, j0 = jt * 32;

    const int w  = tid >> 6;
    const int wr = w >> 1;         // 16-row half
    const int wc = w & 1;          // 16-col half
    const int l  = tid & 63;
    const int lr = l & 15;
    const int lk = l >> 4;

    const int arow = tid >> 3, akq = tid & 7;    // A: 32r x 32k = 256 float4
    const int brow = (tid & 127) >> 2, bko = tid & 3;  // B: 32r x 32k = 128 uint4 (waves 0-1)

    f32x4 c0 = {0.f, 0.f, 0.f, 0.f};

    float4 aN = *(const float4*)&AO[(size_t)(r0 + arow) * EMB + akq * 4];
    uint4  bN;
    if (tid < 128) bN = *(const uint4*)&Wob[(size_t)(j0 + brow) * EMB + bko * 8];

    for (int kt = 0; kt < 32; ++kt) {
        __syncthreads();
        *(ushort4*)&As[arow * 40 + akq * 4] = f2bf4(aN);
        if (tid < 128) *(uint4*)&Bs[brow * 40 + bko * 8] = bN;
        if (kt < 31) {                       // prefetch k-step kt+1
            const int kb = (kt + 1) * 32;
            aN = *(const float4*)&AO[(size_t)(r0 + arow) * EMB + kb + akq * 4];
            if (tid < 128) bN = *(const uint4*)&Wob[(size_t)(j0 + brow) * EMB + kb + bko * 8];
        }
        __syncthreads();

        const bf16x8 a  = *(const bf16x8*)&As[(wr * 16 + lr) * 40 + lk * 8];
        const bf16x8 b0 = *(const bf16x8*)&Bs[(wc * 16 + lr) * 40 + lk * 8];
        c0 = __builtin_amdgcn_mfma_f32_16x16x32_bf16(a, b0, c0, 0, 0, 0);
    }

    const int rbase = r0 + wr * 16 + lk * 4;
    const int jbase = j0 + wc * 16 + lr;
    const float bb0 = bo[jbase];
#pragma unroll
    for (int e = 0; e < 4; ++e) {
        out[(size_t)(rbase + e) * EMB + jbase] = c0[e] + bb0;
    }
}

extern "C" void kernel_launch(void* const* d_in, const int* in_sizes, int n_in,
                              void* d_out, int out_size, void* d_ws, size_t ws_size,
                              hipStream_t stream)
{
    const float* x  = (const float*)d_in[0];
    const float* Wq = (const float*)d_in[1];
    const float* Wk = (const float*)d_in[2];
    const float* Wv = (const float*)d_in[3];
    const float* Wo = (const float*)d_in[4];
    const float* bo = (const float*)d_in[5];

    float* ws = (float*)d_ws;
    ushortT* Q   = (ushortT*)ws;              // 524288 bf16 = 1 MB
    ushortT* K   = (ushortT*)(ws + 262144);   // 1 MB
    ushortT* V   = (ushortT*)(ws + 524288);   // 1 MB
    float*   AO  = ws + 786432;               // 524288 f32 = 2 MB
    ushortT* Wob = (ushortT*)(ws + 1310720);  // 1048576 bf16 = 2 MB

    qkv_kernel<<<256, 256, 0, stream>>>(x, Wq, Wk, Wv, Wo, Q, K, V, AO, Wob);
    attn_kernel<<<2048, 256, 0, stream>>>(Q, K, V, AO);
    proj_kernel<<<512, 256, 0, stream>>>(AO, Wob, bo, (float*)d_out);
}

// Round 24
// 48.070 us; speedup vs baseline: 1.7844x; 1.0443x over previous
//
#include <hip/hip_runtime.h>

#define NB 2
#define SQL 256
#define NH 16
#define HD 64
#define EMB 1024

typedef unsigned short ushortT;
typedef unsigned int uintT;
typedef __attribute__((ext_vector_type(8))) short bf16x8;
typedef __attribute__((ext_vector_type(4))) float f32x4;
typedef __attribute__((ext_vector_type(2))) float f32x2;

// log2(e) / sqrt(EMBED): folded into Wq so softmax = 2^(q*k)
__device__ __constant__ float kQSCALE = 1.4426950408889634f / 32.0f;

__device__ __forceinline__ float fexp2(float x) { return __builtin_amdgcn_exp2f(x); }
__device__ __forceinline__ float frcp(float x)  { return __builtin_amdgcn_rcpf(x); }

__device__ __forceinline__ ushortT f2bf(float x) {
    uintT u = __float_as_uint(x);
    u += 0x7fffu + ((u >> 16) & 1u);        // RNE
    return (ushortT)(u >> 16);
}
__device__ __forceinline__ ushort4 f2bf4(float4 a) {
    return make_ushort4(f2bf(a.x), f2bf(a.y), f2bf(a.z), f2bf(a.w));
}
// unpack one uint32 = 2 bf16 (lo = even channel, hi = odd channel) -> f32x2
__device__ __forceinline__ f32x2 unpk2(uintT u) {
    f32x2 r;
    r.x = __uint_as_float(u << 16);
    r.y = __uint_as_float(u & 0xffff0000u);
    return r;
}
// pair-sum via DPP quad_perm [1,0,3,2]: lane(2i) <-> lane(2i+1). VALU pipe.
__device__ __forceinline__ float pairsum_dpp(float u) {
    const int j = __builtin_amdgcn_mov_dpp(__float_as_int(u), 0xB1, 0xF, 0xF, true);
    return u + __int_as_float(j);
}

// ---------------------------------------------------------------------------
// Kernel 1: q/k/v projections via bf16 MFMA (16x16x32). Block = 2 (n,s) rows.
// Folds: AO = 0 (attn atomic target), Wo -> bf16 (Wob). Grid 256 x 256.
// ---------------------------------------------------------------------------
__global__ __launch_bounds__(256) void qkv_kernel(
    const float* __restrict__ x,
    const float* __restrict__ Wq,
    const float* __restrict__ Wk,
    const float* __restrict__ Wv,
    const float* __restrict__ Wo,
    ushortT* __restrict__ Q,
    ushortT* __restrict__ K,
    ushortT* __restrict__ V,
    float* __restrict__ AO,
    ushortT* __restrict__ Wob)
{
    __shared__ ushortT wls[3][64 * 72];
    __shared__ ushortT xs[2][16 * 72];

    const int tid = threadIdx.x;
    const int ns0 = blockIdx.x * 2;
    const int g   = blockIdx.x * 256 + tid;   // 65536 threads total

    // fold: AO = 0 (2 float4/thread)
    {
        const float4 z = make_float4(0.f, 0.f, 0.f, 0.f);
        ((float4*)AO)[g] = z;
        ((float4*)AO)[g + 65536] = z;
    }
    // fold: Wo -> bf16 (1M floats, 4 float4/thread)
#pragma unroll
    for (int j = 0; j < 4; ++j) {
        const int f4 = j * 65536 + g;
        ((ushort4*)Wob)[f4] = f2bf4(((const float4*)Wo)[f4]);
    }

#pragma unroll
    for (int m = 0; m < 3; ++m) {
        const float4* src = (m == 0) ? (const float4*)Wq
                          : (m == 1) ? (const float4*)Wk : (const float4*)Wv;
#pragma unroll
        for (int j = 0; j < 4; ++j) {
            const int idx = j * 256 + tid;
            const int e   = idx >> 4;
            const int d4  = idx & 15;
            float4 a = src[idx];
            if (m == 0) { a.x *= kQSCALE; a.y *= kQSCALE; a.z *= kQSCALE; a.w *= kQSCALE; }
            *(ushort4*)&wls[m][e * 72 + d4 * 4] = f2bf4(a);
        }
    }
#pragma unroll
    for (int j = 0; j < 2; ++j) {
        const int idx = j * 256 + tid;
        const int r   = idx >> 8;
        const int h   = (idx >> 4) & 15;
        const int d4  = idx & 15;
        const float4 a = ((const float4*)(x + (size_t)(ns0 + r) * EMB))[idx & 255];
        *(ushort4*)&xs[r][h * 72 + d4 * 4] = f2bf4(a);
    }
    __syncthreads();

    const int w   = tid >> 6;
    const int nsr = w >> 1;
    const int eb0 = (w & 1) * 32;
    const int l   = tid & 63;
    const int lr  = l & 15;
    const int lk  = l >> 4;

    const bf16x8 a0 = *(const bf16x8*)&xs[nsr][lr * 72 + lk * 8];
    const bf16x8 a1 = *(const bf16x8*)&xs[nsr][lr * 72 + 32 + lk * 8];

#pragma unroll
    for (int m = 0; m < 3; ++m) {
        ushortT* outp = (m == 0) ? Q : (m == 1) ? K : V;
#pragma unroll
        for (int ef = 0; ef < 2; ++ef) {
            const int eb = eb0 + ef * 16;
            const bf16x8 b0 = *(const bf16x8*)&wls[m][(eb + lr) * 72 + lk * 8];
            const bf16x8 b1 = *(const bf16x8*)&wls[m][(eb + lr) * 72 + 32 + lk * 8];
            f32x4 c = {0.f, 0.f, 0.f, 0.f};
            c = __builtin_amdgcn_mfma_f32_16x16x32_bf16(a0, b0, c, 0, 0, 0);
            c = __builtin_amdgcn_mfma_f32_16x16x32_bf16(a1, b1, c, 0, 0, 0);
            ushortT* dst = outp + (size_t)(ns0 + nsr) * EMB + (eb + lr) * 16 + lk * 4;
            *(ushort4*)dst = make_ushort4(f2bf(c[0]), f2bf(c[1]), f2bf(c[2]), f2bf(c[3]));
        }
    }
}

// ---------------------------------------------------------------------------
// Kernel 2: fused energy -> softmax(h) -> sum(t). Measured-best version:
// wave = 2 s-streams x 8ch packed f32x2, DPP pair-sum, ping-pong register
// prefetch (K 2 iters / V 1 iter ahead), peeled tail (no over-reads); 4
// waves split a 64-wide t-window; LDS tree-reduce; 4 atomicAdd/thread.
// Grid = 2n * 128sg * 2eh * 4tw = 2048 blocks x 256 threads (8 waves/SIMD).
// ---------------------------------------------------------------------------
#define ATTN_STEP(KU4, VU4)                                                    \
    {                                                                          \
        f32x2 k2[4], v2[4], p0[4], p1[4];                                      \
        k2[0] = unpk2(KU4.x); k2[1] = unpk2(KU4.y);                            \
        k2[2] = unpk2(KU4.z); k2[3] = unpk2(KU4.w);                            \
        _Pragma("unroll")                                                      \
        for (int j = 0; j < 4; ++j) {                                          \
            const f32x2 x0 = q0_2[j] * k2[j];                                  \
            const f32x2 x1 = q1_2[j] * k2[j];                                  \
            p0[j].x = fexp2(x0.x); p0[j].y = fexp2(x0.y);                      \
            p1[j].x = fexp2(x1.x); p1[j].y = fexp2(x1.y);                      \
        }                                                                      \
        const f32x2 s0v = (p0[0] + p0[1]) + (p0[2] + p0[3]);                   \
        const f32x2 s1v = (p1[0] + p1[1]) + (p1[2] + p1[3]);                   \
        const float rs0 = frcp(pairsum_dpp(s0v.x + s0v.y));                    \
        const float rs1 = frcp(pairsum_dpp(s1v.x + s1v.y));                    \
        const f32x2 rb0 = {rs0, rs0};                                          \
        const f32x2 rb1 = {rs1, rs1};                                          \
        v2[0] = unpk2(VU4.x); v2[1] = unpk2(VU4.y);                            \
        v2[2] = unpk2(VU4.z); v2[3] = unpk2(VU4.w);                            \
        _Pragma("unroll")                                                      \
        for (int j = 0; j < 4; ++j) {                                          \
            acc0[j] = __builtin_elementwise_fma(v2[j] * rb0, p0[j], acc0[j]);  \
            acc1[j] = __builtin_elementwise_fma(v2[j] * rb1, p1[j], acc1[j]);  \
        }                                                                      \
    }

__global__ __launch_bounds__(256) void attn_kernel(
    const ushortT* __restrict__ Q,
    const ushortT* __restrict__ K,
    const ushortT* __restrict__ V,
    float* __restrict__ AO)
{
    __shared__ float red[16][256];   // 16 KB, bank-conflict-free

    const int b    = blockIdx.x;
    const int tw   = b & 3;
    const int eh   = (b >> 2) & 1;
    const int sg   = (b >> 3) & 127;
    const int n    = b >> 10;
    const int wave = threadIdx.x >> 6;
    const int l    = threadIdx.x & 63;
    const int s0   = sg * 2;
    const int t0   = tw * 64 + wave * 16;   // each wave: 16 t-steps

    f32x2 q0_2[4], q1_2[4];
    {
        const uint4* qp = (const uint4*)(Q + (size_t)(n * SQL + s0) * EMB + 512 * eh) + l;
        const uint4 qa = qp[0];
        const uint4 qb = qp[128];   // next s row
        q0_2[0] = unpk2(qa.x); q0_2[1] = unpk2(qa.y);
        q0_2[2] = unpk2(qa.z); q0_2[3] = unpk2(qa.w);
        q1_2[0] = unpk2(qb.x); q1_2[1] = unpk2(qb.y);
        q1_2[2] = unpk2(qb.z); q1_2[3] = unpk2(qb.w);
    }

    f32x2 acc0[4], acc1[4];
#pragma unroll
    for (int j = 0; j < 4; ++j) {
        acc0[j] = (f32x2){0.f, 0.f};
        acc1[j] = (f32x2){0.f, 0.f};
    }

    const uint4* kp = (const uint4*)(K + (size_t)(n * SQL + t0) * EMB + 512 * eh) + l;
    const uint4* vp = (const uint4*)(V + (size_t)(n * SQL + t0) * EMB + 512 * eh) + l;

    uint4 ka = kp[0];      // k(t)
    uint4 kb = kp[128];    // k(t+1)
    uint4 va = vp[0];      // v(t)

#pragma unroll
    for (int tt = 0; tt < 14; tt += 2) {
        const uint4 kn2 = kp[256];   // k(t+2)
        const uint4 vb  = vp[128];   // v(t+1)
        ATTN_STEP(ka, va);           // consume t
        const uint4 kn3 = kp[384];   // k(t+3)
        va = vp[256];                // v(t+2)
        kp += 256; vp += 256;
        ATTN_STEP(kb, vb);           // consume t+1
        ka = kn2; kb = kn3;
    }
    {   // peeled final pair: no prefetch -> zero over-reads
        const uint4 vb = vp[128];
        ATTN_STEP(ka, va);
        ATTN_STEP(kb, vb);
    }

    // ---- cross-wave LDS reduction: value i = s*8 + c (s in {0,1}, c in 0..7)
#pragma unroll
    for (int j = 0; j < 4; ++j) {
        red[2 * j        ][wave * 64 + l] = acc0[j].x;
        red[2 * j + 1    ][wave * 64 + l] = acc0[j].y;
        red[8 + 2 * j    ][wave * 64 + l] = acc1[j].x;
        red[8 + 2 * j + 1][wave * 64 + l] = acc1[j].y;
    }
    __syncthreads();

    // element = 512eh + 8l + c -> AO channel = 512(l&1) + 64c + 32eh + (l>>1)
    float* aob = AO + (size_t)(n * SQL + s0) * EMB + 512 * (l & 1) + 32 * eh + (l >> 1);
#pragma unroll
    for (int di = 0; di < 4; ++di) {
        const int i = wave * 4 + di;
        const float sum = (red[i][l] + red[i][64 + l]) + (red[i][128 + l] + red[i][192 + l]);
        const int s = i >> 3;
        const int c = i & 7;
        atomicAdd(aob + (size_t)s * EMB + 64 * c, sum);
    }
}

// ---------------------------------------------------------------------------
// Kernel 3: out = AO @ Wob^T + bias via bf16 MFMA. 32r x 64j tile, FULL K
// (32 k-steps) with register prefetch of next k-step's A/B. Plain stores +
// fused bias -> zero atomics. Grid = 16rt * 16jt = 256 blocks x 256 threads.
// (Measured-best proj; 32x32 variant regressed in round 23.)
// ---------------------------------------------------------------------------
__global__ __launch_bounds__(256) void proj_kernel(
    const float* __restrict__ AO,
    const ushortT* __restrict__ Wob,
    const float* __restrict__ bo,
    float* __restrict__ out)
{
    __shared__ ushortT As[32 * 40];
    __shared__ ushortT Bs[64 * 40];

    const int b  = blockIdx.x;     // 0..255
    const int jt = b & 15;         // cols
    const int rt = b >> 4;         // 0..15 -> 512 rows
    const int tid = threadIdx.x;
    const int r0 = rt * 32, j0 = jt * 64;

    const int w  = tid >> 6;
    const int wr = w >> 1;         // 16-row half
    const int wc = w & 1;          // 32-col half
    const int l  = tid & 63;
    const int lr = l & 15;
    const int lk = l >> 4;

    const int arow = tid >> 3, akq = tid & 7;   // A: 32r x 32k = 256 float4
    const int brow = tid >> 2, bko = tid & 3;   // B: 64r x 32k = 256 uint4

    f32x4 c0 = {0.f, 0.f, 0.f, 0.f};
    f32x4 c1 = {0.f, 0.f, 0.f, 0.f};

    float4 aN = *(const float4*)&AO[(size_t)(r0 + arow) * EMB + akq * 4];
    uint4  bN = *(const uint4*)&Wob[(size_t)(j0 + brow) * EMB + bko * 8];

    for (int kt = 0; kt < 32; ++kt) {
        __syncthreads();
        *(ushort4*)&As[arow * 40 + akq * 4] = f2bf4(aN);
        *(uint4*)&Bs[brow * 40 + bko * 8] = bN;
        if (kt < 31) {                       // prefetch k-step kt+1
            const int kb = (kt + 1) * 32;
            aN = *(const float4*)&AO[(size_t)(r0 + arow) * EMB + kb + akq * 4];
            bN = *(const uint4*)&Wob[(size_t)(j0 + brow) * EMB + kb + bko * 8];
        }
        __syncthreads();

        const bf16x8 a  = *(const bf16x8*)&As[(wr * 16 + lr) * 40 + lk * 8];
        const bf16x8 b0 = *(const bf16x8*)&Bs[(wc * 32 + lr) * 40 + lk * 8];
        const bf16x8 b1 = *(const bf16x8*)&Bs[(wc * 32 + 16 + lr) * 40 + lk * 8];
        c0 = __builtin_amdgcn_mfma_f32_16x16x32_bf16(a, b0, c0, 0, 0, 0);
        c1 = __builtin_amdgcn_mfma_f32_16x16x32_bf16(a, b1, c1, 0, 0, 0);
    }

    const int rbase = r0 + wr * 16 + lk * 4;
    const int jbase = j0 + wc * 32 + lr;
    const float bb0 = bo[jbase];
    const float bb1 = bo[jbase + 16];
#pragma unroll
    for (int e = 0; e < 4; ++e) {
        out[(size_t)(rbase + e) * EMB + jbase]      = c0[e] + bb0;
        out[(size_t)(rbase + e) * EMB + jbase + 16] = c1[e] + bb1;
    }
}

extern "C" void kernel_launch(void* const* d_in, const int* in_sizes, int n_in,
                              void* d_out, int out_size, void* d_ws, size_t ws_size,
                              hipStream_t stream)
{
    const float* x  = (const float*)d_in[0];
    const float* Wq = (const float*)d_in[1];
    const float* Wk = (const float*)d_in[2];
    const float* Wv = (const float*)d_in[3];
    const float* Wo = (const float*)d_in[4];
    const float* bo = (const float*)d_in[5];

    float* ws = (float*)d_ws;
    ushortT* Q   = (ushortT*)ws;              // 524288 bf16 = 1 MB
    ushortT* K   = (ushortT*)(ws + 262144);   // 1 MB
    ushortT* V   = (ushortT*)(ws + 524288);   // 1 MB
    float*   AO  = ws + 786432;               // 524288 f32 = 2 MB
    ushortT* Wob = (ushortT*)(ws + 1310720);  // 1048576 bf16 = 2 MB

    qkv_kernel<<<256, 256, 0, stream>>>(x, Wq, Wk, Wv, Wo, Q, K, V, AO, Wob);
    attn_kernel<<<2048, 256, 0, stream>>>(Q, K, V, AO);
    proj_kernel<<<256, 256, 0, stream>>>(AO, Wob, bo, (float*)d_out);
}